// Round 2
// baseline (685.017 us; speedup 1.0000x reference)
//
#include <hip/hip_runtime.h>

typedef short s16x8 __attribute__((ext_vector_type(8)));
typedef unsigned short u16x8 __attribute__((ext_vector_type(8)));
typedef float f32x4 __attribute__((ext_vector_type(4)));

__device__ __forceinline__ float b2f(unsigned short u) {
    union { unsigned int i; float f; } x; x.i = ((unsigned int)u) << 16; return x.f;
}
__device__ __forceinline__ unsigned short f2b(float f) {
    union { float f; unsigned int i; } x; x.f = f;
    unsigned int r = (x.i + 0x7fffu + ((x.i >> 16) & 1u)) >> 16;
    return (unsigned short)r;
}
// read input element i: mode==1 -> fp32 buffer, mode==0 -> bf16 buffer
__device__ __forceinline__ float ldin(const void* p, size_t i, int mode) {
    return mode ? ((const float*)p)[i] : b2f(((const unsigned short*)p)[i]);
}
__device__ __forceinline__ float wave_sum(float v) {
    for (int off = 32; off; off >>= 1) v += __shfl_xor(v, off, 64);
    return v;
}
__device__ __forceinline__ float sigm(float x) { return 1.f / (1.f + __expf(-x)); }

// ---- dtype detector: bf16 emb has |x|<=0.089 -> exponent field <= 0x7B.
// fp32 emb read as ushorts: low halves are random mantissa bits -> exp>=0x7D certain.
__global__ void k_detect(const unsigned short* __restrict__ emb, int* __restrict__ flag) {
    int bad = 0;
    for (int i = threadIdx.x; i < 2048; i += 256) {
        unsigned e = (emb[i] >> 7) & 0xFFu;
        if (e >= 0x7Du) bad = 1;
    }
    if (bad) atomicOr(flag, 1);
}

// ---- row 1/max(||x||,eps) for all embedding rows (D=128), wave per row ----
__global__ void k_inv_norm(const void* __restrict__ emb, float* __restrict__ invn, int NI,
                           const int* __restrict__ md) {
    int mode = *md;
    int w = threadIdx.x >> 6, l = threadIdx.x & 63;
    int row = blockIdx.x * 4 + w;
    if (row >= NI) return;
    float a = ldin(emb, (size_t)row * 128 + l, mode);
    float b = ldin(emb, (size_t)row * 128 + l + 64, mode);
    float ss = wave_sum(a * a + b * b);
    if (l == 0) invn[row] = 1.f / fmaxf(sqrtf(ss), 1e-12f);
}

// ---- feat[v] = l2norm(emb[iid[v]]) -> bf16, wave per row ----
__global__ void k_gather_norm(const void* __restrict__ emb, const int* __restrict__ iid,
                              unsigned short* __restrict__ outb, int n, const int* __restrict__ md) {
    int mode = *md;
    int w = threadIdx.x >> 6, l = threadIdx.x & 63;
    int row = blockIdx.x * 4 + w;
    if (row >= n) return;
    size_t base = (size_t)iid[row] * 128;
    float a = ldin(emb, base + l, mode);
    float b = ldin(emb, base + l + 64, mode);
    float ss = wave_sum(a * a + b * b);
    float inv = 1.f / fmaxf(sqrtf(ss), 1e-12f);
    outb[(size_t)row * 128 + l] = f2b(a * inv);
    outb[(size_t)row * 128 + l + 64] = f2b(b * inv);
}

// ---- edge scatter: m1[dst]+=f[src]*w, m2[src]+=f[dst]*w, ws1[dst]+=w, ws2[src]+=w ----
__global__ void k_edge(const unsigned short* __restrict__ featb, const int* __restrict__ src,
                       const int* __restrict__ dst, const void* __restrict__ ew,
                       float* __restrict__ m1, float* __restrict__ m2,
                       float* __restrict__ ws1, float* __restrict__ ws2,
                       const int* __restrict__ md) {
    int mode = *md;
    int e = blockIdx.x, d = threadIdx.x;
    int s = src[e], t = dst[e];
    float w = ldin(ew, e, mode);
    float fs = b2f(featb[(size_t)s * 128 + d]);
    float ft = b2f(featb[(size_t)t * 128 + d]);
    atomicAdd(&m1[(size_t)t * 128 + d], fs * w);
    atomicAdd(&m2[(size_t)s * 128 + d], ft * w);
    if (d == 0) { atomicAdd(&ws1[t], w); atomicAdd(&ws2[s], w); }
}

// ---- agg = ws>0 ? m/max(ws,eps) : 0 -> bf16 ----
__global__ void k_aggdiv(const float* __restrict__ m1, const float* __restrict__ m2,
                         const float* __restrict__ ws1, const float* __restrict__ ws2,
                         unsigned short* __restrict__ agg1, unsigned short* __restrict__ agg2, int n) {
    int i = blockIdx.x * blockDim.x + threadIdx.x;
    if (i >= n * 128) return;
    int v = i >> 7;
    float w1 = ws1[v], w2 = ws2[v];
    agg1[i] = f2b(w1 > 0.f ? m1[i] / fmaxf(w1, 1e-12f) : 0.f);
    agg2[i] = f2b(w2 > 0.f ? m2[i] / fmaxf(w2, 1e-12f) : 0.f);
}

// ---- C[M,N] = A[M,K] @ B[N,K]^T. A is internal bf16 scratch; B is an INPUT buffer
// (bf16 or fp32 per mode). EPI: 0 fp32 C, 1 bf16 C, 2: out dtype per mode, *12,
// + rowsum[m] += exp(12*c). binv: optional B row scale. ----
template<int EPI>
__global__ __launch_bounds__(256) void gemm_bt(const unsigned short* __restrict__ A,
                                               const void* __restrict__ B,
                                               const float* __restrict__ binv,
                                               void* __restrict__ Cp, float* __restrict__ rowsum,
                                               int M, int N, int K, int ldc,
                                               const int* __restrict__ md) {
    __shared__ unsigned short As[64][72];
    __shared__ unsigned short Bs[64][72];
    int mode = *md;
    int tid = threadIdx.x;
    int tn = blockIdx.x * 64, tm = blockIdx.y * 64;
    int w = tid >> 6, l = tid & 63, q = l >> 4, r = l & 15;

    f32x4 acc[4];
#pragma unroll
    for (int j = 0; j < 4; j++) acc[j] = (f32x4){0.f, 0.f, 0.f, 0.f};

    for (int k0 = 0; k0 < K; k0 += 64) {
#pragma unroll
        for (int it = 0; it < 2; it++) {
            int c = tid + 256 * it;      // 512 chunks of 8 elems
            int row = c >> 3, cb = c & 7;
            u16x8 av = *(const u16x8*)(A + (size_t)(tm + row) * K + k0 + cb * 8);
            *(u16x8*)&As[row][cb * 8] = av;
            int rn = tn + row;
            u16x8 bv = {0, 0, 0, 0, 0, 0, 0, 0};
            if (rn < N) {
                float s = binv ? binv[rn] : 1.f;
                if (mode) {
                    const float* Bf = (const float*)B + (size_t)rn * K + k0 + cb * 8;
                    f32x4 lo = *(const f32x4*)Bf;
                    f32x4 hi = *(const f32x4*)(Bf + 4);
#pragma unroll
                    for (int i2 = 0; i2 < 4; i2++) {
                        bv[i2] = f2b(lo[i2] * s);
                        bv[i2 + 4] = f2b(hi[i2] * s);
                    }
                } else {
                    bv = *(const u16x8*)((const unsigned short*)B + (size_t)rn * K + k0 + cb * 8);
                    if (binv) {
#pragma unroll
                        for (int i2 = 0; i2 < 8; i2++) bv[i2] = f2b(b2f(bv[i2]) * s);
                    }
                }
            }
            *(u16x8*)&Bs[row][cb * 8] = bv;
        }
        __syncthreads();
#pragma unroll
        for (int kk = 0; kk < 64; kk += 32) {
            s16x8 a = *(const s16x8*)&As[16 * w + r][kk + 8 * q];
#pragma unroll
            for (int j = 0; j < 4; j++) {
                s16x8 b = *(const s16x8*)&Bs[16 * j + r][kk + 8 * q];
                acc[j] = __builtin_amdgcn_mfma_f32_16x16x32_bf16(a, b, acc[j], 0, 0, 0);
            }
        }
        __syncthreads();
    }

    int gm0 = tm + 16 * w + 4 * q;   // C/D layout: col=lane&15, row=(lane>>4)*4+reg
    if (EPI == 2) {
        float sume[4] = {0.f, 0.f, 0.f, 0.f};
#pragma unroll
        for (int j = 0; j < 4; j++) {
            int gn = tn + 16 * j + r;
            bool ok = gn < N;
#pragma unroll
            for (int p = 0; p < 4; p++) {
                float v = acc[j][p] * 12.f;
                if (ok) {
                    if (mode) ((float*)Cp)[(size_t)(gm0 + p) * ldc + gn] = v;
                    else ((unsigned short*)Cp)[(size_t)(gm0 + p) * ldc + gn] = f2b(v);
                    sume[p] += __expf(v);
                }
            }
        }
#pragma unroll
        for (int p = 0; p < 4; p++) {
            float s = sume[p];
            s += __shfl_xor(s, 1, 64); s += __shfl_xor(s, 2, 64);
            s += __shfl_xor(s, 4, 64); s += __shfl_xor(s, 8, 64);
            if (r == 0) atomicAdd(&rowsum[gm0 + p], s);
        }
    } else {
#pragma unroll
        for (int j = 0; j < 4; j++) {
            int gn = tn + 16 * j + r;
            if (gn < N) {
#pragma unroll
                for (int p = 0; p < 4; p++) {
                    if (EPI == 0) ((float*)Cp)[(size_t)(gm0 + p) * ldc + gn] = acc[j][p];
                    else ((unsigned short*)Cp)[(size_t)(gm0 + p) * ldc + gn] = f2b(acc[j][p]);
                }
            }
        }
    }
}

// ---- GRU gates + l2norm -> feat2 (bf16). 128 thr/node ----
__global__ void k_gru(const float* __restrict__ gi, const float* __restrict__ gh,
                      const void* __restrict__ bih, const void* __restrict__ bhh,
                      const unsigned short* __restrict__ featb, unsigned short* __restrict__ feat2b,
                      const int* __restrict__ md) {
    int mode = *md;
    int v = blockIdx.x, d = threadIdx.x;
    const float* giv = gi + (size_t)v * 384;
    const float* ghv = gh + (size_t)v * 384;
    float ir = giv[d]       + ldin(bih, d, mode);
    float iz = giv[128 + d] + ldin(bih, 128 + d, mode);
    float in = giv[256 + d] + ldin(bih, 256 + d, mode);
    float hr = ghv[d]       + ldin(bhh, d, mode);
    float hz = ghv[128 + d] + ldin(bhh, 128 + d, mode);
    float hn = ghv[256 + d] + ldin(bhh, 256 + d, mode);
    float rg = sigm(ir + hr);
    float zg = sigm(iz + hz);
    float ng = tanhf(in + rg * hn);
    float h = b2f(featb[(size_t)v * 128 + d]);
    float f = (1.f - zg) * ng + zg * h;
    __shared__ float red[2];
    float ss = wave_sum(f * f);
    int w = d >> 6, l = d & 63;
    if (l == 0) red[w] = ss;
    __syncthreads();
    float inv = 1.f / fmaxf(sqrtf(red[0] + red[1]), 1e-12f);
    feat2b[(size_t)v * 128 + d] = f2b(f * inv);
}

// ---- gather last rows; also write sr_l half of sr_in ----
__global__ void k_last(const unsigned short* __restrict__ feat2b, const int* __restrict__ last,
                       unsigned short* __restrict__ lastb, unsigned short* __restrict__ srin) {
    int b = blockIdx.x, d = threadIdx.x;
    unsigned short x = feat2b[(size_t)last[b] * 128 + d];
    lastb[(size_t)b * 128 + d] = x;
    srin[(size_t)b * 256 + d] = x;
}

// ---- e[v] = sum_d sigmoid(fu + fv[seg] + bv) * We ----
__global__ void k_e(const float* __restrict__ fu, const float* __restrict__ fv,
                    const void* __restrict__ bv, const void* __restrict__ We,
                    const int* __restrict__ seg, float* __restrict__ e,
                    const int* __restrict__ md) {
    int mode = *md;
    int v = blockIdx.x, d = threadIdx.x;
    int b = seg[v];
    float x = fu[(size_t)v * 128 + d] + fv[(size_t)b * 128 + d] + ldin(bv, d, mode);
    float p = sigm(x) * ldin(We, d, mode);
    __shared__ float red[2];
    float ss = wave_sum(p);
    int w = d >> 6, l = d & 63;
    if (l == 0) red[w] = ss;
    __syncthreads();
    if (d == 0) e[v] = red[0] + red[1];
}

// ---- per-session softmax over S contiguous nodes + sr_g -> sr_in[:,128:] ----
__global__ void k_seg(const float* __restrict__ e, const unsigned short* __restrict__ feat2b,
                      unsigned short* __restrict__ srin, int S) {
    int b = blockIdx.x, d = threadIdx.x;
    __shared__ float al[32];
    __shared__ float ebuf[32];
    if (d < S) ebuf[d] = e[b * S + d];
    __syncthreads();
    if (d == 0) {
        float m = -1e30f;
        for (int j = 0; j < S; j++) m = fmaxf(m, ebuf[j]);
        float s = 0.f;
        for (int j = 0; j < S; j++) { float x = __expf(ebuf[j] - m); al[j] = x; s += x; }
        float invs = 1.f / s;
        for (int j = 0; j < S; j++) al[j] *= invs;
    }
    __syncthreads();
    float acc = 0.f;
    for (int j = 0; j < S; j++) acc += al[j] * b2f(feat2b[(size_t)(b * S + j) * 128 + d]);
    srin[(size_t)b * 256 + 128 + d] = f2b(acc);
}

// ---- l2norm rows fp32 -> bf16, wave per row ----
__global__ void k_l2row(const float* __restrict__ x, unsigned short* __restrict__ yb, int nrows) {
    int w = threadIdx.x >> 6, l = threadIdx.x & 63;
    int row = blockIdx.x * 4 + w;
    if (row >= nrows) return;
    float a = x[(size_t)row * 128 + l], b = x[(size_t)row * 128 + l + 64];
    float ss = wave_sum(a * a + b * b);
    float inv = 1.f / fmaxf(sqrtf(ss), 1e-12f);
    yb[(size_t)row * 128 + l] = f2b(a * inv);
    yb[(size_t)row * 128 + l + 64] = f2b(b * inv);
}

// ---- out[i] -= log(rowsum[row]), 8 elems/thread, dtype per mode ----
__global__ void k_final(void* __restrict__ out, const float* __restrict__ rowsum,
                        int NI, int total8, const int* __restrict__ md) {
    int mode = *md;
    int i = blockIdx.x * blockDim.x + threadIdx.x;
    if (i >= total8) return;
    size_t base = (size_t)i * 8;
    int row = (int)(base / (size_t)NI);   // NI % 8 == 0 -> chunk never crosses rows
    float lse = logf(rowsum[row]);
    if (mode) {
        float* o = (float*)out + base;
        f32x4 a = *(const f32x4*)o, b = *(const f32x4*)(o + 4);
#pragma unroll
        for (int j = 0; j < 4; j++) { a[j] -= lse; b[j] -= lse; }
        *(f32x4*)o = a; *(f32x4*)(o + 4) = b;
    } else {
        unsigned short* o = (unsigned short*)out + base;
        u16x8 v = *(const u16x8*)o;
#pragma unroll
        for (int j = 0; j < 8; j++) v[j] = f2b(b2f(v[j]) - lse);
        *(u16x8*)o = v;
    }
}

extern "C" void kernel_launch(void* const* d_in, const int* in_sizes, int n_in,
                              void* d_out, int out_size, void* d_ws, size_t ws_size,
                              hipStream_t stream) {
    const int* iid  = (const int*)d_in[0];
    const int* esrc = (const int*)d_in[1];
    const int* edst = (const int*)d_in[2];
    const void* ew  = d_in[3];
    const int* last = (const int*)d_in[4];
    const int* seg  = (const int*)d_in[5];
    const void* emb = d_in[6];
    const void* W1  = d_in[7];
    const void* W2  = d_in[8];
    const void* wih = d_in[9];
    const void* whh = d_in[10];
    const void* bih = d_in[11];
    const void* bhh = d_in[12];
    const void* Wu  = d_in[13];
    const void* Wv  = d_in[14];
    const void* bv  = d_in[15];
    const void* We  = d_in[16];
    const void* Wsr = d_in[17];

    const int N = in_sizes[0];        // 10240 nodes
    const int E = in_sizes[1];        // 9216 edges
    const int B = in_sizes[4];        // 1024 sessions
    const int NI = in_sizes[6] / 128; // 50000 items
    const int S = N / B;              // 10

    // ---- scratch laid out inside d_out (>=102.4MB; all consumed before final GEMM) ----
    char* ob = (char*)d_out;
    float* m1  = (float*)ob;
    float* m2  = m1 + (size_t)N * 128;
    float* ws1 = m2 + (size_t)N * 128;
    float* ws2 = ws1 + N;
    unsigned short* agg1  = (unsigned short*)(ws2 + N);
    unsigned short* agg2  = agg1 + (size_t)N * 128;
    unsigned short* featb = agg2 + (size_t)N * 128;
    unsigned short* hnb   = featb + (size_t)N * 128;           // N x 256
    float* gi = (float*)(hnb + (size_t)N * 256);               // N x 384
    float* gh = gi + (size_t)N * 384;                          // N x 384
    unsigned short* feat2b = (unsigned short*)(gh + (size_t)N * 384);
    unsigned short* lastb  = feat2b + (size_t)N * 128;
    unsigned short* srin   = lastb + (size_t)B * 128;          // B x 256
    float* fu  = (float*)(srin + (size_t)B * 256);             // N x 128
    float* fv  = fu + (size_t)N * 128;                         // B x 128
    float* ev  = fv + (size_t)B * 128;                         // N
    float* sr0 = ev + N;                                       // B x 128

    // ---- small persistent scratch in d_ws (~0.5MB) ----
    float* invn = (float*)d_ws;                                // NI floats
    unsigned short* srb = (unsigned short*)((char*)d_ws + (((size_t)NI * 4 + 255) & ~(size_t)255));
    float* rowsum = (float*)(srb + (size_t)B * 128);           // B floats
    int* flag = (int*)(rowsum + B);                            // dtype mode flag

    hipMemsetAsync(m1, 0, ((size_t)2 * N * 128 + 2 * N) * 4, stream);
    hipMemsetAsync(rowsum, 0, (size_t)B * 4 + 64, stream);     // rowsum + flag

    k_detect<<<dim3(1), 256, 0, stream>>>((const unsigned short*)emb, flag);

    k_inv_norm<<<dim3((NI + 3) / 4), 256, 0, stream>>>(emb, invn, NI, flag);
    k_gather_norm<<<dim3((N + 3) / 4), 256, 0, stream>>>(emb, iid, featb, N, flag);
    k_edge<<<dim3(E), 128, 0, stream>>>(featb, esrc, edst, ew, m1, m2, ws1, ws2, flag);
    k_aggdiv<<<dim3((N * 128 + 255) / 256), 256, 0, stream>>>(m1, m2, ws1, ws2, agg1, agg2, N);

    gemm_bt<1><<<dim3(2, N / 64), 256, 0, stream>>>(agg1, W1, nullptr, hnb,       nullptr, N, 128, 128, 256, flag);
    gemm_bt<1><<<dim3(2, N / 64), 256, 0, stream>>>(agg2, W2, nullptr, hnb + 128, nullptr, N, 128, 128, 256, flag);
    gemm_bt<0><<<dim3(6, N / 64), 256, 0, stream>>>(hnb,   wih, nullptr, gi, nullptr, N, 384, 256, 384, flag);
    gemm_bt<0><<<dim3(6, N / 64), 256, 0, stream>>>(featb, whh, nullptr, gh, nullptr, N, 384, 128, 384, flag);

    k_gru<<<dim3(N), 128, 0, stream>>>(gi, gh, bih, bhh, featb, feat2b, flag);
    k_last<<<dim3(B), 128, 0, stream>>>(feat2b, last, lastb, srin);

    gemm_bt<0><<<dim3(2, N / 64), 256, 0, stream>>>(feat2b, Wu, nullptr, fu, nullptr, N, 128, 128, 128, flag);
    gemm_bt<0><<<dim3(2, B / 64), 256, 0, stream>>>(lastb,  Wv, nullptr, fv, nullptr, B, 128, 128, 128, flag);

    k_e<<<dim3(N), 128, 0, stream>>>(fu, fv, bv, We, seg, ev, flag);
    k_seg<<<dim3(B), 128, 0, stream>>>(ev, feat2b, srin, S);

    gemm_bt<0><<<dim3(2, B / 64), 256, 0, stream>>>(srin, Wsr, nullptr, sr0, nullptr, B, 128, 256, 128, flag);
    k_l2row<<<dim3((B + 3) / 4), 256, 0, stream>>>(sr0, srb, B);

    // big fused GEMM: logits*12 -> d_out (dtype per mode) + per-row sum(exp)
    gemm_bt<2><<<dim3((NI + 63) / 64, B / 64), 256, 0, stream>>>(srb, emb, invn, d_out, rowsum, B, NI, 128, NI, flag);

    int total8 = (int)(((size_t)B * NI) / 8);
    k_final<<<dim3((total8 + 255) / 256), 256, 0, stream>>>(d_out, rowsum, NI, total8, flag);
}

// Round 3
// 467.693 us; speedup vs baseline: 1.4647x; 1.4647x over previous
//
#include <hip/hip_runtime.h>

typedef short s16x8 __attribute__((ext_vector_type(8)));
typedef unsigned short u16x8 __attribute__((ext_vector_type(8)));
typedef float f32x4 __attribute__((ext_vector_type(4)));

__device__ __forceinline__ float b2f(unsigned short u) {
    union { unsigned int i; float f; } x; x.i = ((unsigned int)u) << 16; return x.f;
}
__device__ __forceinline__ unsigned short f2b(float f) {
    union { float f; unsigned int i; } x; x.f = f;
    unsigned int r = (x.i + 0x7fffu + ((x.i >> 16) & 1u)) >> 16;
    return (unsigned short)r;
}
// read input element i: mode==1 -> fp32 buffer, mode==0 -> bf16 buffer
__device__ __forceinline__ float ldin(const void* p, size_t i, int mode) {
    return mode ? ((const float*)p)[i] : b2f(((const unsigned short*)p)[i]);
}
__device__ __forceinline__ float wave_sum(float v) {
    for (int off = 32; off; off >>= 1) v += __shfl_xor(v, off, 64);
    return v;
}
__device__ __forceinline__ float sigm(float x) { return 1.f / (1.f + __expf(-x)); }

// ---- dtype detector: bf16 emb has |x|<=0.089 -> exponent field <= 0x7B.
// fp32 emb read as ushorts: low halves are random mantissa bits -> exp>=0x7D certain.
__global__ void k_detect(const unsigned short* __restrict__ emb, int* __restrict__ flag) {
    int bad = 0;
    for (int i = threadIdx.x; i < 2048; i += 256) {
        unsigned e = (emb[i] >> 7) & 0xFFu;
        if (e >= 0x7Du) bad = 1;
    }
    if (bad) atomicOr(flag, 1);
}

// ---- row 1/max(||x||,eps) for all embedding rows (D=128), wave per row ----
__global__ void k_inv_norm(const void* __restrict__ emb, float* __restrict__ invn, int NI,
                           const int* __restrict__ md) {
    int mode = *md;
    int w = threadIdx.x >> 6, l = threadIdx.x & 63;
    int row = blockIdx.x * 4 + w;
    if (row >= NI) return;
    float a = ldin(emb, (size_t)row * 128 + l, mode);
    float b = ldin(emb, (size_t)row * 128 + l + 64, mode);
    float ss = wave_sum(a * a + b * b);
    if (l == 0) invn[row] = 1.f / fmaxf(sqrtf(ss), 1e-12f);
}

// ---- feat[v] = l2norm(emb[iid[v]]) -> bf16, wave per row ----
__global__ void k_gather_norm(const void* __restrict__ emb, const int* __restrict__ iid,
                              unsigned short* __restrict__ outb, int n, const int* __restrict__ md) {
    int mode = *md;
    int w = threadIdx.x >> 6, l = threadIdx.x & 63;
    int row = blockIdx.x * 4 + w;
    if (row >= n) return;
    size_t base = (size_t)iid[row] * 128;
    float a = ldin(emb, base + l, mode);
    float b = ldin(emb, base + l + 64, mode);
    float ss = wave_sum(a * a + b * b);
    float inv = 1.f / fmaxf(sqrtf(ss), 1e-12f);
    outb[(size_t)row * 128 + l] = f2b(a * inv);
    outb[(size_t)row * 128 + l + 64] = f2b(b * inv);
}

// ---- edge scatter ----
__global__ void k_edge(const unsigned short* __restrict__ featb, const int* __restrict__ src,
                       const int* __restrict__ dst, const void* __restrict__ ew,
                       float* __restrict__ m1, float* __restrict__ m2,
                       float* __restrict__ ws1, float* __restrict__ ws2,
                       const int* __restrict__ md) {
    int mode = *md;
    int e = blockIdx.x, d = threadIdx.x;
    int s = src[e], t = dst[e];
    float w = ldin(ew, e, mode);
    float fs = b2f(featb[(size_t)s * 128 + d]);
    float ft = b2f(featb[(size_t)t * 128 + d]);
    atomicAdd(&m1[(size_t)t * 128 + d], fs * w);
    atomicAdd(&m2[(size_t)s * 128 + d], ft * w);
    if (d == 0) { atomicAdd(&ws1[t], w); atomicAdd(&ws2[s], w); }
}

// ---- agg = ws>0 ? m/max(ws,eps) : 0 -> bf16 ----
__global__ void k_aggdiv(const float* __restrict__ m1, const float* __restrict__ m2,
                         const float* __restrict__ ws1, const float* __restrict__ ws2,
                         unsigned short* __restrict__ agg1, unsigned short* __restrict__ agg2, int n) {
    int i = blockIdx.x * blockDim.x + threadIdx.x;
    if (i >= n * 128) return;
    int v = i >> 7;
    float w1 = ws1[v], w2 = ws2[v];
    agg1[i] = f2b(w1 > 0.f ? m1[i] / fmaxf(w1, 1e-12f) : 0.f);
    agg2[i] = f2b(w2 > 0.f ? m2[i] / fmaxf(w2, 1e-12f) : 0.f);
}

// ---- small GEMM: C[M,N] = A[M,K] @ B[N,K]^T. EPI: 0 fp32 C, 1 bf16 C ----
template<int EPI>
__global__ __launch_bounds__(256) void gemm_bt(const unsigned short* __restrict__ A,
                                               const void* __restrict__ B,
                                               void* __restrict__ Cp,
                                               int M, int N, int K, int ldc,
                                               const int* __restrict__ md) {
    __shared__ unsigned short As[64][72];
    __shared__ unsigned short Bs[64][72];
    int mode = *md;
    int tid = threadIdx.x;
    int tn = blockIdx.x * 64, tm = blockIdx.y * 64;
    int w = tid >> 6, l = tid & 63, q = l >> 4, r = l & 15;

    f32x4 acc[4];
#pragma unroll
    for (int j = 0; j < 4; j++) acc[j] = (f32x4){0.f, 0.f, 0.f, 0.f};

    for (int k0 = 0; k0 < K; k0 += 64) {
#pragma unroll
        for (int it = 0; it < 2; it++) {
            int c = tid + 256 * it;
            int row = c >> 3, cb = c & 7;
            u16x8 av = *(const u16x8*)(A + (size_t)(tm + row) * K + k0 + cb * 8);
            *(u16x8*)&As[row][cb * 8] = av;
            int rn = tn + row;
            u16x8 bv = {0, 0, 0, 0, 0, 0, 0, 0};
            if (rn < N) {
                if (mode) {
                    const float* Bf = (const float*)B + (size_t)rn * K + k0 + cb * 8;
                    f32x4 lo = *(const f32x4*)Bf;
                    f32x4 hi = *(const f32x4*)(Bf + 4);
#pragma unroll
                    for (int i2 = 0; i2 < 4; i2++) { bv[i2] = f2b(lo[i2]); bv[i2 + 4] = f2b(hi[i2]); }
                } else {
                    bv = *(const u16x8*)((const unsigned short*)B + (size_t)rn * K + k0 + cb * 8);
                }
            }
            *(u16x8*)&Bs[row][cb * 8] = bv;
        }
        __syncthreads();
#pragma unroll
        for (int kk = 0; kk < 64; kk += 32) {
            s16x8 a = *(const s16x8*)&As[16 * w + r][kk + 8 * q];
#pragma unroll
            for (int j = 0; j < 4; j++) {
                s16x8 b = *(const s16x8*)&Bs[16 * j + r][kk + 8 * q];
                acc[j] = __builtin_amdgcn_mfma_f32_16x16x32_bf16(a, b, acc[j], 0, 0, 0);
            }
        }
        __syncthreads();
    }

    int gm0 = tm + 16 * w + 4 * q;
#pragma unroll
    for (int j = 0; j < 4; j++) {
        int gn = tn + 16 * j + r;
        if (gn < N) {
#pragma unroll
            for (int p = 0; p < 4; p++) {
                if (EPI == 0) ((float*)Cp)[(size_t)(gm0 + p) * ldc + gn] = acc[j][p];
                else ((unsigned short*)Cp)[(size_t)(gm0 + p) * ldc + gn] = f2b(acc[j][p]);
            }
        }
    }
}

// ---- big logits GEMM, strip-persistent, two-pass.
// PASS 1: rowsum[m] += sum_n exp(12 * (A.emb_n) * invn_n)  (no C writes)
// PASS 2: out[m][n] = 12*(A.emb_n)*invn_n - log(rowsum[m])  (coalesced via LDS)
// A [M x 128] bf16 in registers (per-wave frags); B streamed via dbuf LDS with
// global-side XOR swizzle so frag ds_read_b128 is conflict-free.
template<int PASS>
__global__ __launch_bounds__(256) void k_logits(const unsigned short* __restrict__ A,
                                                const void* __restrict__ emb,
                                                const float* __restrict__ invn,
                                                float* __restrict__ rowsum,
                                                void* __restrict__ out,
                                                int NI, int NT,
                                                const int* __restrict__ md) {
    extern __shared__ unsigned short smem[];
    unsigned short* Bs = smem;            // [2][64][128] = 32KB
    unsigned short* Cs = smem + 16384;    // [64][68] bf16 (pass2 mode0 only)
    const int mode = *md;
    const int tid = threadIdx.x;
    const int w = tid >> 6, l = tid & 63, q = l >> 4, r = l & 15;
    const int tm = blockIdx.y * 64;
    const int gmb = tm + 16 * w + 4 * q;

    // A fragments in registers, loaded once (16 VGPRs)
    s16x8 af[4];
    {
        const unsigned short* Ap = A + (size_t)(tm + 16 * w + r) * 128 + 8 * q;
#pragma unroll
        for (int t = 0; t < 4; t++) af[t] = *(const s16x8*)(Ap + 32 * t);
    }

    float lse4[4];
    if (PASS == 2) {
#pragma unroll
        for (int p = 0; p < 4; p++) lse4[p] = logf(rowsum[gmb + p]);
    }
    float sume[4] = {0.f, 0.f, 0.f, 0.f};

    const int T0 = blockIdx.x * NT;

    auto stage = [&](int buf, int n0) {
        unsigned short* dst = Bs + buf * 8192;
        if (mode == 0 && n0 + 64 <= NI) {
#pragma unroll
            for (int it = 0; it < 4; it++) {
                int c = tid + 256 * it;          // 1024 chunks of 16B
                int row = c >> 4, cb = c & 15;
                int gcb = cb ^ (row & 7);        // global-side swizzle
                const unsigned short* g = (const unsigned short*)emb + (size_t)(n0 + row) * 128 + gcb * 8;
                __builtin_amdgcn_global_load_lds(
                    (const __attribute__((address_space(1))) unsigned int*)g,
                    (__attribute__((address_space(3))) unsigned int*)(dst + (size_t)c * 8),
                    16, 0, 0);
            }
        } else {
#pragma unroll
            for (int it = 0; it < 4; it++) {
                int c = tid + 256 * it;
                int row = c >> 4, cb = c & 15;
                int gcb = cb ^ (row & 7);
                int rn = n0 + row;
                u16x8 bv = {0, 0, 0, 0, 0, 0, 0, 0};
                if (rn < NI) {
                    if (mode) {
                        const float* gf = (const float*)emb + (size_t)rn * 128 + gcb * 8;
                        f32x4 lo = *(const f32x4*)gf, hi = *(const f32x4*)(gf + 4);
#pragma unroll
                        for (int i2 = 0; i2 < 4; i2++) { bv[i2] = f2b(lo[i2]); bv[i2 + 4] = f2b(hi[i2]); }
                    } else {
                        bv = *(const u16x8*)((const unsigned short*)emb + (size_t)rn * 128 + gcb * 8);
                    }
                }
                *(u16x8*)(dst + (size_t)c * 8) = bv;
            }
        }
    };

    if (T0 * 64 < NI) stage(0, T0 * 64);

    for (int nt = 0; nt < NT; nt++) {
        int n0 = (T0 + nt) * 64;
        if (n0 >= NI) break;
        __syncthreads();                               // Bs[cur] ready; prev Cs reads done
        bool do_pf = (nt + 1 < NT) && ((T0 + nt + 1) * 64 < NI);
        if (PASS == 1 || mode != 0) {
            if (do_pf) stage((nt + 1) & 1, (T0 + nt + 1) * 64);   // covered by MFMA+epi
        }

        const unsigned short* Bt = Bs + (nt & 1) * 8192;
        f32x4 acc[4];
#pragma unroll
        for (int j = 0; j < 4; j++) acc[j] = (f32x4){0.f, 0.f, 0.f, 0.f};
#pragma unroll
        for (int j = 0; j < 4; j++) {
            int rn = 16 * j + r;
#pragma unroll
            for (int t = 0; t < 4; t++) {
                int cb2 = (4 * t + q) ^ (r & 7);
                s16x8 b = *(const s16x8*)(Bt + rn * 128 + cb2 * 8);
                acc[j] = __builtin_amdgcn_mfma_f32_16x16x32_bf16(af[t], b, acc[j], 0, 0, 0);
            }
        }

        if (PASS == 1) {
#pragma unroll
            for (int j = 0; j < 4; j++) {
                int gn = n0 + 16 * j + r;
                bool ok = gn < NI;
                float iv = ok ? invn[gn] * 12.f : 0.f;
#pragma unroll
                for (int p = 0; p < 4; p++) if (ok) sume[p] += __expf(acc[j][p] * iv);
            }
        } else if (mode == 0) {
            // stage C-tile to LDS, then 128B-coalesced row stores
#pragma unroll
            for (int j = 0; j < 4; j++) {
                int gn = n0 + 16 * j + r;
                float iv = (gn < NI) ? invn[gn] * 12.f : 0.f;
                int nl = 16 * j + r;
#pragma unroll
                for (int p = 0; p < 4; p++)
                    Cs[(16 * w + 4 * q + p) * 68 + nl] = f2b(acc[j][p] * iv - lse4[p]);
            }
            __syncthreads();                           // Cs ready; Bs[cur] reads done
            if (do_pf) stage((nt + 1) & 1, (T0 + nt + 1) * 64);   // covered by stores
            int ml = tid >> 2, cc = tid & 3;
            int colb = cc * 16;
            unsigned short* gp = (unsigned short*)out + (size_t)(tm + ml) * NI + n0 + colb;
            const unsigned short* cp = Cs + ml * 68 + colb;
            if (n0 + colb + 16 <= NI) {
                *(u16x8*)gp = *(const u16x8*)cp;
                *(u16x8*)(gp + 8) = *(const u16x8*)(cp + 8);
            } else {
                for (int jj = 0; jj < 16; jj++)
                    if (n0 + colb + jj < NI) gp[jj] = cp[jj];
            }
        } else {
            float* gout = (float*)out;
#pragma unroll
            for (int j = 0; j < 4; j++) {
                int gn = n0 + 16 * j + r;
                if (gn < NI) {
                    float iv = invn[gn] * 12.f;
#pragma unroll
                    for (int p = 0; p < 4; p++)
                        gout[(size_t)(gmb + p) * NI + gn] = acc[j][p] * iv - lse4[p];
                }
            }
        }
    }

    if (PASS == 1) {
#pragma unroll
        for (int p = 0; p < 4; p++) {
            float s = sume[p];
            s += __shfl_xor(s, 1, 64); s += __shfl_xor(s, 2, 64);
            s += __shfl_xor(s, 4, 64); s += __shfl_xor(s, 8, 64);
            if (r == 0) atomicAdd(&rowsum[gmb + p], s);
        }
    }
}

// ---- GRU gates + l2norm -> feat2 (bf16). 128 thr/node ----
__global__ void k_gru(const float* __restrict__ gi, const float* __restrict__ gh,
                      const void* __restrict__ bih, const void* __restrict__ bhh,
                      const unsigned short* __restrict__ featb, unsigned short* __restrict__ feat2b,
                      const int* __restrict__ md) {
    int mode = *md;
    int v = blockIdx.x, d = threadIdx.x;
    const float* giv = gi + (size_t)v * 384;
    const float* ghv = gh + (size_t)v * 384;
    float ir = giv[d]       + ldin(bih, d, mode);
    float iz = giv[128 + d] + ldin(bih, 128 + d, mode);
    float in = giv[256 + d] + ldin(bih, 256 + d, mode);
    float hr = ghv[d]       + ldin(bhh, d, mode);
    float hz = ghv[128 + d] + ldin(bhh, 128 + d, mode);
    float hn = ghv[256 + d] + ldin(bhh, 256 + d, mode);
    float rg = sigm(ir + hr);
    float zg = sigm(iz + hz);
    float ng = tanhf(in + rg * hn);
    float h = b2f(featb[(size_t)v * 128 + d]);
    float f = (1.f - zg) * ng + zg * h;
    __shared__ float red[2];
    float ss = wave_sum(f * f);
    int w = d >> 6, l = d & 63;
    if (l == 0) red[w] = ss;
    __syncthreads();
    float inv = 1.f / fmaxf(sqrtf(red[0] + red[1]), 1e-12f);
    feat2b[(size_t)v * 128 + d] = f2b(f * inv);
}

// ---- gather last rows; also write sr_l half of sr_in ----
__global__ void k_last(const unsigned short* __restrict__ feat2b, const int* __restrict__ last,
                       unsigned short* __restrict__ lastb, unsigned short* __restrict__ srin) {
    int b = blockIdx.x, d = threadIdx.x;
    unsigned short x = feat2b[(size_t)last[b] * 128 + d];
    lastb[(size_t)b * 128 + d] = x;
    srin[(size_t)b * 256 + d] = x;
}

// ---- e[v] = sum_d sigmoid(fu + fv[seg] + bv) * We ----
__global__ void k_e(const float* __restrict__ fu, const float* __restrict__ fv,
                    const void* __restrict__ bv, const void* __restrict__ We,
                    const int* __restrict__ seg, float* __restrict__ e,
                    const int* __restrict__ md) {
    int mode = *md;
    int v = blockIdx.x, d = threadIdx.x;
    int b = seg[v];
    float x = fu[(size_t)v * 128 + d] + fv[(size_t)b * 128 + d] + ldin(bv, d, mode);
    float p = sigm(x) * ldin(We, d, mode);
    __shared__ float red[2];
    float ss = wave_sum(p);
    int w = d >> 6, l = d & 63;
    if (l == 0) red[w] = ss;
    __syncthreads();
    if (d == 0) e[v] = red[0] + red[1];
}

// ---- per-session softmax over S contiguous nodes + sr_g -> sr_in[:,128:] ----
__global__ void k_seg(const float* __restrict__ e, const unsigned short* __restrict__ feat2b,
                      unsigned short* __restrict__ srin, int S) {
    int b = blockIdx.x, d = threadIdx.x;
    __shared__ float al[32];
    __shared__ float ebuf[32];
    if (d < S) ebuf[d] = e[b * S + d];
    __syncthreads();
    if (d == 0) {
        float m = -1e30f;
        for (int j = 0; j < S; j++) m = fmaxf(m, ebuf[j]);
        float s = 0.f;
        for (int j = 0; j < S; j++) { float x = __expf(ebuf[j] - m); al[j] = x; s += x; }
        float invs = 1.f / s;
        for (int j = 0; j < S; j++) al[j] *= invs;
    }
    __syncthreads();
    float acc = 0.f;
    for (int j = 0; j < S; j++) acc += al[j] * b2f(feat2b[(size_t)(b * S + j) * 128 + d]);
    srin[(size_t)b * 256 + 128 + d] = f2b(acc);
}

// ---- l2norm rows fp32 -> bf16, wave per row ----
__global__ void k_l2row(const float* __restrict__ x, unsigned short* __restrict__ yb, int nrows) {
    int w = threadIdx.x >> 6, l = threadIdx.x & 63;
    int row = blockIdx.x * 4 + w;
    if (row >= nrows) return;
    float a = x[(size_t)row * 128 + l], b = x[(size_t)row * 128 + l + 64];
    float ss = wave_sum(a * a + b * b);
    float inv = 1.f / fmaxf(sqrtf(ss), 1e-12f);
    yb[(size_t)row * 128 + l] = f2b(a * inv);
    yb[(size_t)row * 128 + l + 64] = f2b(b * inv);
}

extern "C" void kernel_launch(void* const* d_in, const int* in_sizes, int n_in,
                              void* d_out, int out_size, void* d_ws, size_t ws_size,
                              hipStream_t stream) {
    const int* iid  = (const int*)d_in[0];
    const int* esrc = (const int*)d_in[1];
    const int* edst = (const int*)d_in[2];
    const void* ew  = d_in[3];
    const int* last = (const int*)d_in[4];
    const int* seg  = (const int*)d_in[5];
    const void* emb = d_in[6];
    const void* W1  = d_in[7];
    const void* W2  = d_in[8];
    const void* wih = d_in[9];
    const void* whh = d_in[10];
    const void* bih = d_in[11];
    const void* bhh = d_in[12];
    const void* Wu  = d_in[13];
    const void* Wv  = d_in[14];
    const void* bv  = d_in[15];
    const void* We  = d_in[16];
    const void* Wsr = d_in[17];

    const int N = in_sizes[0];        // 10240 nodes
    const int E = in_sizes[1];        // 9216 edges
    const int B = in_sizes[4];        // 1024 sessions
    const int NI = in_sizes[6] / 128; // 50000 items
    const int S = N / B;              // 10

    // ---- scratch laid out inside d_out (all consumed before pass-2 overwrites) ----
    char* ob = (char*)d_out;
    float* m1  = (float*)ob;
    float* m2  = m1 + (size_t)N * 128;
    float* ws1 = m2 + (size_t)N * 128;
    float* ws2 = ws1 + N;
    unsigned short* agg1  = (unsigned short*)(ws2 + N);
    unsigned short* agg2  = agg1 + (size_t)N * 128;
    unsigned short* featb = agg2 + (size_t)N * 128;
    unsigned short* hnb   = featb + (size_t)N * 128;           // N x 256
    float* gi = (float*)(hnb + (size_t)N * 256);               // N x 384
    float* gh = gi + (size_t)N * 384;                          // N x 384
    unsigned short* feat2b = (unsigned short*)(gh + (size_t)N * 384);
    unsigned short* lastb  = feat2b + (size_t)N * 128;
    unsigned short* srin   = lastb + (size_t)B * 128;          // B x 256
    float* fu  = (float*)(srin + (size_t)B * 256);             // N x 128
    float* fv  = fu + (size_t)N * 128;                         // B x 128
    float* ev  = fv + (size_t)B * 128;                         // N
    float* sr0 = ev + N;                                       // B x 128

    // ---- small persistent scratch in d_ws ----
    float* invn = (float*)d_ws;                                // NI floats
    unsigned short* srb = (unsigned short*)((char*)d_ws + (((size_t)NI * 4 + 255) & ~(size_t)255));
    float* rowsum = (float*)(srb + (size_t)B * 128);           // B floats
    int* flag = (int*)(rowsum + B);                            // dtype mode flag

    hipMemsetAsync(m1, 0, ((size_t)2 * N * 128 + 2 * N) * 4, stream);
    hipMemsetAsync(rowsum, 0, (size_t)B * 4 + 64, stream);     // rowsum + flag

    k_detect<<<dim3(1), 256, 0, stream>>>((const unsigned short*)emb, flag);

    k_inv_norm<<<dim3((NI + 3) / 4), 256, 0, stream>>>(emb, invn, NI, flag);
    k_gather_norm<<<dim3((N + 3) / 4), 256, 0, stream>>>(emb, iid, featb, N, flag);
    k_edge<<<dim3(E), 128, 0, stream>>>(featb, esrc, edst, ew, m1, m2, ws1, ws2, flag);
    k_aggdiv<<<dim3((N * 128 + 255) / 256), 256, 0, stream>>>(m1, m2, ws1, ws2, agg1, agg2, N);

    gemm_bt<1><<<dim3(2, N / 64), 256, 0, stream>>>(agg1, W1, hnb,       N, 128, 128, 256, flag);
    gemm_bt<1><<<dim3(2, N / 64), 256, 0, stream>>>(agg2, W2, hnb + 128, N, 128, 128, 256, flag);
    gemm_bt<0><<<dim3(6, N / 64), 256, 0, stream>>>(hnb,   wih, gi, N, 384, 256, 384, flag);
    gemm_bt<0><<<dim3(6, N / 64), 256, 0, stream>>>(featb, whh, gh, N, 384, 128, 384, flag);

    k_gru<<<dim3(N), 128, 0, stream>>>(gi, gh, bih, bhh, featb, feat2b, flag);
    k_last<<<dim3(B), 128, 0, stream>>>(feat2b, last, lastb, srin);

    gemm_bt<0><<<dim3(2, N / 64), 256, 0, stream>>>(feat2b, Wu, fu, N, 128, 128, 128, flag);
    gemm_bt<0><<<dim3(2, B / 64), 256, 0, stream>>>(lastb,  Wv, fv, B, 128, 128, 128, flag);

    k_e<<<dim3(N), 128, 0, stream>>>(fu, fv, bv, We, seg, ev, flag);
    k_seg<<<dim3(B), 128, 0, stream>>>(ev, feat2b, srin, S);

    gemm_bt<0><<<dim3(2, B / 64), 256, 0, stream>>>(srin, Wsr, sr0, B, 128, 256, 128, flag);
    k_l2row<<<dim3((B + 3) / 4), 256, 0, stream>>>(sr0, srb, B);

    // ---- two-pass fused logits + log-softmax ----
    const int NT = 14;                                  // n-tiles per strip
    int ntile = (NI + 63) / 64;                         // 782
    int strips = (ntile + NT - 1) / NT;                 // 56
    k_logits<1><<<dim3(strips, B / 64), 256, 32768, stream>>>(srb, emb, invn, rowsum, d_out, NI, NT, flag);
    k_logits<2><<<dim3(strips, B / 64), 256, 32768 + 64 * 68 * 2, stream>>>(srb, emb, invn, rowsum, d_out, NI, NT, flag);
}